// Round 2
// baseline (253.663 us; speedup 1.0000x reference)
//
#include <hip/hip_runtime.h>
#include <hip/hip_bf16.h>
#include <math.h>

using bf16 = __hip_bfloat16;
typedef __attribute__((ext_vector_type(8))) short bf16x8;
typedef __attribute__((ext_vector_type(8))) short short8;
typedef __attribute__((ext_vector_type(4))) float f32x4;

#define AS1 __attribute__((address_space(1)))
#define AS3 __attribute__((address_space(3)))

constexpr int BATCH = 4;
constexpr int SEQ   = 4096;
constexpr int DIM   = 2048;
constexpr int SCAN  = 128;
constexpr int STATE = 16;
constexpr int LCH   = 128;        // scan chunk length
constexpr int NCH   = SEQ / LCH;  // 32 chunks

__device__ __forceinline__ float bf2f(bf16 v) { return __bfloat162float(v); }
__device__ __forceinline__ bf16  f2bf(float v) { return __float2bfloat16(v); }

// ---------------------------------------------------------------------------
// Probe: decide whether device buffers are f32 (flag=0) or bf16 (flag=1).
// Read 512 values of x as bf16; bf16 data ~100% in exponent range, f32 data
// read as bf16 ~58% (low halves are ~uniform bits). Threshold 80%.
// ---------------------------------------------------------------------------
__global__ void kprobe(const unsigned short* __restrict__ x, int* __restrict__ flag) {
  int t = threadIdx.x;   // 64 threads
  int cnt = 0;
#pragma unroll
  for (int i = 0; i < 8; ++i) {
    unsigned short u = x[t * 8 + i];
    int e = (u >> 7) & 0xFF;
    if (e >= 107 && e <= 147) ++cnt;   // |v| roughly in [2^-20, 2^20], excl NaN/Inf
  }
  cnt += __shfl_xor(cnt, 1);  cnt += __shfl_xor(cnt, 2);
  cnt += __shfl_xor(cnt, 4);  cnt += __shfl_xor(cnt, 8);
  cnt += __shfl_xor(cnt, 16); cnt += __shfl_xor(cnt, 32);
  if (t == 0) *flag = (cnt >= 410) ? 1 : 0;
}

// ---------------------------------------------------------------------------
// Convert x -> bf16 workspace copy (f32 mode converts; bf16 mode raw copy)
// ---------------------------------------------------------------------------
__global__ __launch_bounds__(256) void kconv_x(const void* __restrict__ xin,
                                               bf16* __restrict__ xb,
                                               const int* __restrict__ flag) {
  const size_t N = (size_t)BATCH * SEQ * DIM;   // 33.55M
  size_t nt  = (size_t)gridDim.x * blockDim.x;
  size_t tid = (size_t)blockIdx.x * blockDim.x + threadIdx.x;
  if (*flag) {
    const float4* s = (const float4*)xin;     // raw 16B copy
    float4* d = (float4*)xb;
    for (size_t i = tid; i < N / 8; i += nt) d[i] = s[i];
  } else {
    const float4* s = (const float4*)xin;
    for (size_t i = tid; i < N / 4; i += nt) {
      float4 v = s[i];
      union { short s4 __attribute__((ext_vector_type(4))); bf16 b[4]; } u;
      u.b[0] = f2bf(v.x); u.b[1] = f2bf(v.y); u.b[2] = f2bf(v.z); u.b[3] = f2bf(v.w);
      *(decltype(u.s4)*)&xb[i * 4] = u.s4;
    }
  }
}

// ---------------------------------------------------------------------------
// Convert all weights -> bf16 ws copies; b_dt/A_log -> f32 ws copies.
// ---------------------------------------------------------------------------
__device__ __forceinline__ void conv_b(const void* src, bf16* dst, int n, int f,
                                       int gtid, int nt) {
  if (f) { const bf16* s = (const bf16*)src;  for (int i = gtid; i < n; i += nt) dst[i] = s[i]; }
  else   { const float* s = (const float*)src; for (int i = gtid; i < n; i += nt) dst[i] = f2bf(s[i]); }
}
__device__ __forceinline__ void conv_f(const void* src, float* dst, int n, int f,
                                       int gtid, int nt) {
  if (f) { const bf16* s = (const bf16*)src;  for (int i = gtid; i < n; i += nt) dst[i] = bf2f(s[i]); }
  else   { const float* s = (const float*)src; for (int i = gtid; i < n; i += nt) dst[i] = s[i]; }
}

__global__ __launch_bounds__(256) void kconv_w(
    const void* Wi, const void* Wg, const void* Wo, const void* Wdt,
    const void* Wb, const void* Wc, const void* bdt, const void* Alog,
    bf16* Wib, bf16* Wgb, bf16* Wob, bf16* Wdtb, bf16* Wbb, bf16* Wcb,
    float* bdtf, float* Alogf, const int* __restrict__ flag) {
  int f = *flag;
  int nt = gridDim.x * blockDim.x;
  int g  = blockIdx.x * blockDim.x + threadIdx.x;
  conv_b(Wi,  Wib,  SCAN * DIM,  f, g, nt);
  conv_b(Wg,  Wgb,  SCAN * DIM,  f, g, nt);
  conv_b(Wo,  Wob,  DIM * SCAN,  f, g, nt);
  conv_b(Wdt, Wdtb, SCAN * SCAN, f, g, nt);
  conv_b(Wb,  Wbb,  STATE * SCAN, f, g, nt);
  conv_b(Wc,  Wcb,  STATE * SCAN, f, g, nt);
  conv_f(bdt,  bdtf,  SCAN,         f, g, nt);
  conv_f(Alog, Alogf, SCAN * STATE, f, g, nt);
}

// ---------------------------------------------------------------------------
// 128x128 bf16 GEMM tile machinery (A:[M,K] row-major, W:[N,K] row-major)
// ---------------------------------------------------------------------------
__device__ __forceinline__ void stage_tile(const bf16* __restrict__ src, int ld, int k0,
                                           char* ldsbuf, int tid) {
  int w = tid >> 6;
#pragma unroll
  for (int i = 0; i < 4; ++i) {
    int off = i * 4096 + tid * 16;
    int r   = off >> 7;
    int c   = (off & 127) >> 1;
    const bf16* g = src + (size_t)r * ld + (k0 + c);
    char* lb = ldsbuf + i * 4096 + w * 1024;   // wave-uniform base; HW adds lane*16
    __builtin_amdgcn_global_load_lds((const AS1 void*)g, (AS3 void*)lb, 16, 0, 0);
  }
}

__device__ __forceinline__ void compute_tile(const char* ldsA, const char* ldsB,
                                             int tid, f32x4 acc[4][4]) {
  int l  = tid & 63;
  int w  = tid >> 6;
  int wr = (w >> 1) * 64;
  int wc = (w & 1) * 64;
  int lr = l & 15;
  int lk = (l >> 4) * 8;
#pragma unroll
  for (int kk = 0; kk < 64; kk += 32) {
    bf16x8 a[4], b[4];
#pragma unroll
    for (int m = 0; m < 4; ++m)
      a[m] = *(const bf16x8*)(ldsA + ((wr + m * 16 + lr) * 64 + kk + lk) * 2);
#pragma unroll
    for (int n = 0; n < 4; ++n)
      b[n] = *(const bf16x8*)(ldsB + ((wc + n * 16 + lr) * 64 + kk + lk) * 2);
#pragma unroll
    for (int m = 0; m < 4; ++m)
#pragma unroll
      for (int n = 0; n < 4; ++n)
        acc[m][n] = __builtin_amdgcn_mfma_f32_16x16x32_bf16(a[m], b[n], acc[m][n], 0, 0, 0);
  }
}

__device__ __forceinline__ void gemm128(const bf16* Atile, const bf16* Wtile,
                                        int K, char* lds, int tid, f32x4 acc[4][4]) {
  const int nk = K / 64;
  stage_tile(Atile, K, 0, lds, tid);
  stage_tile(Wtile, K, 0, lds + 16384, tid);
  __syncthreads();
  int cur = 0;
  for (int t = 0; t < nk; ++t) {
    int nxt = cur ^ 1;
    if (t + 1 < nk) {
      stage_tile(Atile, K, (t + 1) * 64, lds + nxt * 32768, tid);
      stage_tile(Wtile, K, (t + 1) * 64, lds + nxt * 32768 + 16384, tid);
    }
    compute_tile(lds + cur * 32768, lds + cur * 32768 + 16384, tid, acc);
    __syncthreads();
    cur = nxt;
  }
}

// ---------------------------------------------------------------------------
// K1: z = xb @ Wi^T (bf16), gate = silu(xb @ Wg^T) (bf16).  grid(128, 2)
// ---------------------------------------------------------------------------
__global__ __launch_bounds__(256, 2) void k1_zg(const bf16* __restrict__ x,
                                                const bf16* __restrict__ Wi,
                                                const bf16* __restrict__ Wg,
                                                bf16* __restrict__ z,
                                                bf16* __restrict__ gate) {
  __shared__ char lds[65536];
  int tid = threadIdx.x;
  int mb  = blockIdx.x;
  int sel = blockIdx.y;
  const bf16* W = sel ? Wg : Wi;
  f32x4 acc[4][4];
#pragma unroll
  for (int m = 0; m < 4; ++m)
#pragma unroll
    for (int n = 0; n < 4; ++n)
#pragma unroll
      for (int j = 0; j < 4; ++j) acc[m][n][j] = 0.f;

  gemm128(x + (size_t)mb * 128 * DIM, W, DIM, lds, tid, acc);

  int l  = tid & 63, w = tid >> 6;
  int wr = (w >> 1) * 64, wc = (w & 1) * 64;
  int lr = l & 15, lj = (l >> 4) * 4;
  bf16* o = sel ? gate : z;
#pragma unroll
  for (int m = 0; m < 4; ++m)
#pragma unroll
    for (int n = 0; n < 4; ++n)
#pragma unroll
      for (int j = 0; j < 4; ++j) {
        int row = mb * 128 + wr + m * 16 + lj + j;
        int col = wc + n * 16 + lr;
        float v = acc[m][n][j];
        if (sel) v = v / (1.f + expf(-v));   // silu
        o[(size_t)row * SCAN + col] = f2bf(v);
      }
}

// ---------------------------------------------------------------------------
// K2: dt = softplus(z @ Wdt^T + b_dt), Bv = z @ Wb^T, Cv = z @ Wc^T (fp32 out)
// ---------------------------------------------------------------------------
__global__ __launch_bounds__(256, 2) void k2_small(
    const bf16* __restrict__ z, const bf16* __restrict__ Wdt,
    const bf16* __restrict__ Wb, const bf16* __restrict__ Wc,
    const float* __restrict__ bdtf,
    float* __restrict__ dt, float* __restrict__ Bv, float* __restrict__ Cv) {
  __shared__ bf16 wl[160][136];   // +8 pad: kills ds_read bank conflicts
  __shared__ bf16 zl[64][136];
  int tid = threadIdx.x;
  int m0  = blockIdx.x * 64;

  for (int idx = tid; idx < 160 * 16; idx += 256) {
    int r = idx >> 4, c8 = (idx & 15) << 3;
    const bf16* src;
    if (r < 128)      src = Wdt + r * 128;
    else if (r < 144) src = Wb + (r - 128) * 128;
    else              src = Wc + (r - 144) * 128;
    *(short8*)&wl[r][c8] = *(const short8*)(src + c8);
  }
  for (int idx = tid; idx < 64 * 16; idx += 256) {
    int r = idx >> 4, c8 = (idx & 15) << 3;
    *(short8*)&zl[r][c8] = *(const short8*)(z + (size_t)(m0 + r) * SCAN + c8);
  }
  __syncthreads();

  int l = tid & 63, w = tid >> 6;
  int lr = l & 15, lk = (l >> 4) * 8, lj = (l >> 4) * 4;
  f32x4 acc[10];
#pragma unroll
  for (int n = 0; n < 10; ++n)
#pragma unroll
    for (int j = 0; j < 4; ++j) acc[n][j] = 0.f;

#pragma unroll
  for (int kk = 0; kk < 128; kk += 32) {
    bf16x8 a = *(const bf16x8*)&zl[w * 16 + lr][kk + lk];
#pragma unroll
    for (int n = 0; n < 10; ++n) {
      bf16x8 bfr = *(const bf16x8*)&wl[n * 16 + lr][kk + lk];
      acc[n] = __builtin_amdgcn_mfma_f32_16x16x32_bf16(a, bfr, acc[n], 0, 0, 0);
    }
  }

#pragma unroll
  for (int n = 0; n < 10; ++n) {
    int o = n * 16 + lr;
#pragma unroll
    for (int j = 0; j < 4; ++j) {
      int row = m0 + w * 16 + lj + j;
      float v = acc[n][j];
      if (o < 128) {
        v += bdtf[o];
        v = fmaxf(v, 0.f) + log1pf(expf(-fabsf(v)));   // stable softplus
        dt[(size_t)row * SCAN + o] = v;
      } else if (o < 144) {
        Bv[(size_t)row * STATE + (o - 128)] = v;
      } else {
        Cv[(size_t)row * STATE + (o - 144)] = v;
      }
    }
  }
}

// ---------------------------------------------------------------------------
// K3a: per-chunk local scan from zero -> final state + decay product.
// ---------------------------------------------------------------------------
__global__ __launch_bounds__(256) void k3a(
    const float* __restrict__ dt, const bf16* __restrict__ z,
    const float* __restrict__ Bv, const float* __restrict__ Alogf,
    float* __restrict__ fin, float* __restrict__ apr) {
  int tid = threadIdx.x;
  int k = tid & 15;
  int unit = tid >> 4;
  int n = blockIdx.x * 16 + unit;
  int ch = blockIdx.y, b = blockIdx.z;
  float Ank = -expf(Alogf[n * STATE + k]);
  int t0 = ch * LCH;
  const float* dtp = dt + ((size_t)b * SEQ + t0) * SCAN + n;
  const bf16*  zp  = z  + ((size_t)b * SEQ + t0) * SCAN + n;
  const float* bp  = Bv + ((size_t)b * SEQ + t0) * STATE + k;
  float st = 0.f, ap = 1.f;
#pragma unroll 4
  for (int t = 0; t < LCH; ++t) {
    float d  = dtp[(size_t)t * SCAN];
    float zv = bf2f(zp[(size_t)t * SCAN]);
    float bb = bp[(size_t)t * STATE];
    float a  = fmaf(d, Ank, 1.f);
    st = fmaf(a, st, d * zv * bb);
    ap *= a;
  }
  size_t o = (((size_t)b * NCH + ch) * SCAN + n) * STATE + k;
  fin[o] = st;
  apr[o] = ap;
}

// ---------------------------------------------------------------------------
// K3b: combine across chunks (sequential over 32, parallel over 8192 channels)
// ---------------------------------------------------------------------------
__global__ __launch_bounds__(256) void k3b(const float* __restrict__ fin,
                                           const float* __restrict__ apr,
                                           float* __restrict__ inc) {
  int c = blockIdx.x * 256 + threadIdx.x;   // 0..8191
  int b = c >> 11;
  int nk = c & 2047;
  float s = 0.f;
  for (int ch = 0; ch < NCH; ++ch) {
    size_t o = ((size_t)b * NCH + ch) * 2048 + nk;
    inc[o] = s;
    s = fmaf(apr[o], s, fin[o]);
  }
}

// ---------------------------------------------------------------------------
// K3c: re-scan with incoming state, emit yg = (sum_k state*C) * gate  (bf16)
// ---------------------------------------------------------------------------
__global__ __launch_bounds__(256) void k3c(
    const float* __restrict__ dt, const bf16* __restrict__ z,
    const float* __restrict__ Bv, const float* __restrict__ Cv,
    const float* __restrict__ Alogf, const float* __restrict__ inc,
    const bf16* __restrict__ gate, bf16* __restrict__ yg) {
  int tid = threadIdx.x;
  int k = tid & 15;
  int unit = tid >> 4;
  int n = blockIdx.x * 16 + unit;
  int ch = blockIdx.y, b = blockIdx.z;
  float Ank = -expf(Alogf[n * STATE + k]);
  int t0 = ch * LCH;
  const float* dtp = dt + ((size_t)b * SEQ + t0) * SCAN + n;
  const bf16*  zp  = z  + ((size_t)b * SEQ + t0) * SCAN + n;
  const float* bp  = Bv + ((size_t)b * SEQ + t0) * STATE + k;
  const float* cp  = Cv + ((size_t)b * SEQ + t0) * STATE + k;
  const bf16*  gp  = gate + ((size_t)b * SEQ + t0) * SCAN + n;
  bf16*        yp  = yg   + ((size_t)b * SEQ + t0) * SCAN + n;
  float st = inc[(((size_t)b * NCH + ch) * SCAN + n) * STATE + k];
#pragma unroll 2
  for (int t = 0; t < LCH; ++t) {
    float d  = dtp[(size_t)t * SCAN];
    float zv = bf2f(zp[(size_t)t * SCAN]);
    float bb = bp[(size_t)t * STATE];
    float cc = cp[(size_t)t * STATE];
    float a  = fmaf(d, Ank, 1.f);
    st = fmaf(a, st, d * zv * bb);
    float pr = st * cc;
    pr += __shfl_xor(pr, 1);
    pr += __shfl_xor(pr, 2);
    pr += __shfl_xor(pr, 4);
    pr += __shfl_xor(pr, 8);
    if (k == 0) yp[(size_t)t * SCAN] = f2bf(pr * bf2f(gp[(size_t)t * SCAN]));
  }
}

// ---------------------------------------------------------------------------
// K4: out = yg @ Wo^T  -> [16384,2048], stored f32 or bf16 per flag. grid(128,16)
// ---------------------------------------------------------------------------
__global__ __launch_bounds__(256, 2) void k4_out(const bf16* __restrict__ yg,
                                                 const bf16* __restrict__ Wo,
                                                 void* __restrict__ outv,
                                                 const int* __restrict__ flag) {
  __shared__ char lds[65536];
  int tid = threadIdx.x;
  int mb = blockIdx.x, nb = blockIdx.y;
  f32x4 acc[4][4];
#pragma unroll
  for (int m = 0; m < 4; ++m)
#pragma unroll
    for (int n = 0; n < 4; ++n)
#pragma unroll
      for (int j = 0; j < 4; ++j) acc[m][n][j] = 0.f;

  gemm128(yg + (size_t)mb * 128 * SCAN, Wo + (size_t)nb * 128 * SCAN, SCAN, lds, tid, acc);

  int f = *flag;
  int l  = tid & 63, w = tid >> 6;
  int wr = (w >> 1) * 64, wc = (w & 1) * 64;
  int lr = l & 15, lj = (l >> 4) * 4;
#pragma unroll
  for (int m = 0; m < 4; ++m)
#pragma unroll
    for (int n = 0; n < 4; ++n)
#pragma unroll
      for (int j = 0; j < 4; ++j) {
        int row = mb * 128 + wr + m * 16 + lj + j;
        int col = nb * 128 + wc + n * 16 + lr;
        size_t off = (size_t)row * DIM + col;
        float v = acc[m][n][j];
        if (f) ((bf16*)outv)[off] = f2bf(v);
        else   ((float*)outv)[off] = v;
      }
}

// ---------------------------------------------------------------------------
extern "C" void kernel_launch(void* const* d_in, const int* in_sizes, int n_in,
                              void* d_out, int out_size, void* d_ws, size_t ws_size,
                              hipStream_t stream) {
  const void* x     = d_in[0];
  const void* Wi    = d_in[1];
  const void* Wo    = d_in[2];
  const void* A_log = d_in[3];
  const void* Wb    = d_in[4];
  const void* Wc    = d_in[5];
  const void* Wdt   = d_in[6];
  const void* b_dt  = d_in[7];
  const void* Wg    = d_in[8];

  const size_t M = (size_t)BATCH * SEQ;   // 16384
  char* p = (char*)d_ws;
  int*   flag = (int*)p;    p += 256;
  bf16*  xb   = (bf16*)p;   p += M * DIM * 2;           // 67.1 MB
  bf16*  Wib  = (bf16*)p;   p += (size_t)SCAN * DIM * 2;
  bf16*  Wgb  = (bf16*)p;   p += (size_t)SCAN * DIM * 2;
  bf16*  Wob  = (bf16*)p;   p += (size_t)DIM * SCAN * 2;
  bf16*  Wdtb = (bf16*)p;   p += (size_t)SCAN * SCAN * 2;
  bf16*  Wbb  = (bf16*)p;   p += (size_t)STATE * SCAN * 2;
  bf16*  Wcb  = (bf16*)p;   p += (size_t)STATE * SCAN * 2;
  float* bdtf = (float*)p;  p += SCAN * 4;
  float* Alogf= (float*)p;  p += (size_t)SCAN * STATE * 4;
  bf16*  z    = (bf16*)p;   p += M * SCAN * 2;
  bf16*  gate = (bf16*)p;   p += M * SCAN * 2;
  bf16*  yg   = (bf16*)p;   p += M * SCAN * 2;
  float* dt   = (float*)p;  p += M * SCAN * 4;
  float* Bv   = (float*)p;  p += M * STATE * 4;
  float* Cv   = (float*)p;  p += M * STATE * 4;
  float* fin  = (float*)p;  p += (size_t)BATCH * NCH * SCAN * STATE * 4;
  float* apr  = (float*)p;  p += (size_t)BATCH * NCH * SCAN * STATE * 4;
  float* inc  = (float*)p;  p += (size_t)BATCH * NCH * SCAN * STATE * 4;

  kprobe  <<<1, 64, 0, stream>>>((const unsigned short*)x, flag);
  kconv_x <<<2048, 256, 0, stream>>>(x, xb, flag);
  kconv_w <<<256, 256, 0, stream>>>(Wi, Wg, Wo, Wdt, Wb, Wc, b_dt, A_log,
                                    Wib, Wgb, Wob, Wdtb, Wbb, Wcb, bdtf, Alogf, flag);
  k1_zg   <<<dim3(128, 2), 256, 0, stream>>>(xb, Wib, Wgb, z, gate);
  k2_small<<<dim3(256), 256, 0, stream>>>(z, Wdtb, Wbb, Wcb, bdtf, dt, Bv, Cv);
  k3a     <<<dim3(8, NCH, BATCH), 256, 0, stream>>>(dt, z, Bv, Alogf, fin, apr);
  k3b     <<<dim3(32), 256, 0, stream>>>(fin, apr, inc);
  k3c     <<<dim3(8, NCH, BATCH), 256, 0, stream>>>(dt, z, Bv, Cv, Alogf, inc, gate, yg);
  k4_out  <<<dim3(128, 16), 256, 0, stream>>>(yg, Wob, d_out, flag);
}

// Round 3
// 213.219 us; speedup vs baseline: 1.1897x; 1.1897x over previous
//
#include <hip/hip_runtime.h>
#include <hip/hip_bf16.h>
#include <math.h>

using bf16 = __hip_bfloat16;
typedef __attribute__((ext_vector_type(8))) short bf16x8;
typedef __attribute__((ext_vector_type(8))) short short8;
typedef __attribute__((ext_vector_type(4))) float f32x4;

#define AS1 __attribute__((address_space(1)))
#define AS3 __attribute__((address_space(3)))

constexpr int BATCH = 4;
constexpr int SEQ   = 4096;
constexpr int DIM   = 2048;
constexpr int SCAN  = 128;
constexpr int STATE = 16;
constexpr int LCH   = 32;         // scan chunk length
constexpr int NCH   = SEQ / LCH;  // 128 chunks

__device__ __forceinline__ float bf2f(bf16 v) { return __bfloat162float(v); }
__device__ __forceinline__ bf16  f2bf(float v) { return __float2bfloat16(v); }

// ---------------------------------------------------------------------------
// Probe: decide whether device buffers are f32 (flag=0) or bf16 (flag=1).
// ---------------------------------------------------------------------------
__global__ void kprobe(const unsigned short* __restrict__ x, int* __restrict__ flag) {
  int t = threadIdx.x;   // 64 threads
  int cnt = 0;
#pragma unroll
  for (int i = 0; i < 8; ++i) {
    unsigned short u = x[t * 8 + i];
    int e = (u >> 7) & 0xFF;
    if (e >= 107 && e <= 147) ++cnt;
  }
  cnt += __shfl_xor(cnt, 1);  cnt += __shfl_xor(cnt, 2);
  cnt += __shfl_xor(cnt, 4);  cnt += __shfl_xor(cnt, 8);
  cnt += __shfl_xor(cnt, 16); cnt += __shfl_xor(cnt, 32);
  if (t == 0) *flag = (cnt >= 410) ? 1 : 0;
}

// ---------------------------------------------------------------------------
// Convert x -> bf16 workspace copy
// ---------------------------------------------------------------------------
__global__ __launch_bounds__(256) void kconv_x(const void* __restrict__ xin,
                                               bf16* __restrict__ xb,
                                               const int* __restrict__ flag) {
  const size_t N = (size_t)BATCH * SEQ * DIM;
  size_t nt  = (size_t)gridDim.x * blockDim.x;
  size_t tid = (size_t)blockIdx.x * blockDim.x + threadIdx.x;
  if (*flag) {
    const float4* s = (const float4*)xin;
    float4* d = (float4*)xb;
    for (size_t i = tid; i < N / 8; i += nt) d[i] = s[i];
  } else {
    const float4* s = (const float4*)xin;
    for (size_t i = tid; i < N / 4; i += nt) {
      float4 v = s[i];
      union { short s4 __attribute__((ext_vector_type(4))); bf16 b[4]; } u;
      u.b[0] = f2bf(v.x); u.b[1] = f2bf(v.y); u.b[2] = f2bf(v.z); u.b[3] = f2bf(v.w);
      *(decltype(u.s4)*)&xb[i * 4] = u.s4;
    }
  }
}

// ---------------------------------------------------------------------------
// Weights -> bf16 ws copies; b_dt -> f32; A_log -> Aneg = -exp(A_log) (f32)
// ---------------------------------------------------------------------------
__device__ __forceinline__ void conv_b(const void* src, bf16* dst, int n, int f,
                                       int gtid, int nt) {
  if (f) { const bf16* s = (const bf16*)src;  for (int i = gtid; i < n; i += nt) dst[i] = s[i]; }
  else   { const float* s = (const float*)src; for (int i = gtid; i < n; i += nt) dst[i] = f2bf(s[i]); }
}
__device__ __forceinline__ void conv_f(const void* src, float* dst, int n, int f,
                                       int gtid, int nt) {
  if (f) { const bf16* s = (const bf16*)src;  for (int i = gtid; i < n; i += nt) dst[i] = bf2f(s[i]); }
  else   { const float* s = (const float*)src; for (int i = gtid; i < n; i += nt) dst[i] = s[i]; }
}
__device__ __forceinline__ void conv_aneg(const void* src, float* dst, int n, int f,
                                          int gtid, int nt) {
  if (f) { const bf16* s = (const bf16*)src;  for (int i = gtid; i < n; i += nt) dst[i] = -expf(bf2f(s[i])); }
  else   { const float* s = (const float*)src; for (int i = gtid; i < n; i += nt) dst[i] = -expf(s[i]); }
}

__global__ __launch_bounds__(256) void kconv_w(
    const void* Wi, const void* Wg, const void* Wo, const void* Wdt,
    const void* Wb, const void* Wc, const void* bdt, const void* Alog,
    bf16* Wib, bf16* Wgb, bf16* Wob, bf16* Wdtb, bf16* Wbb, bf16* Wcb,
    float* bdtf, float* Anegf, const int* __restrict__ flag) {
  int f = *flag;
  int nt = gridDim.x * blockDim.x;
  int g  = blockIdx.x * blockDim.x + threadIdx.x;
  conv_b(Wi,  Wib,  SCAN * DIM,  f, g, nt);
  conv_b(Wg,  Wgb,  SCAN * DIM,  f, g, nt);
  conv_b(Wo,  Wob,  DIM * SCAN,  f, g, nt);
  conv_b(Wdt, Wdtb, SCAN * SCAN, f, g, nt);
  conv_b(Wb,  Wbb,  STATE * SCAN, f, g, nt);
  conv_b(Wc,  Wcb,  STATE * SCAN, f, g, nt);
  conv_f(bdt,  bdtf,  SCAN,          f, g, nt);
  conv_aneg(Alog, Anegf, SCAN * STATE, f, g, nt);
}

// ---------------------------------------------------------------------------
// 128x128 bf16 GEMM tile machinery (A:[M,K] row-major, W:[N,K] row-major)
// ---------------------------------------------------------------------------
__device__ __forceinline__ void stage_tile(const bf16* __restrict__ src, int ld, int k0,
                                           char* ldsbuf, int tid) {
  int w = tid >> 6;
#pragma unroll
  for (int i = 0; i < 4; ++i) {
    int off = i * 4096 + tid * 16;
    int r   = off >> 7;
    int c   = (off & 127) >> 1;
    const bf16* g = src + (size_t)r * ld + (k0 + c);
    char* lb = ldsbuf + i * 4096 + w * 1024;
    __builtin_amdgcn_global_load_lds((const AS1 void*)g, (AS3 void*)lb, 16, 0, 0);
  }
}

__device__ __forceinline__ void compute_tile(const char* ldsA, const char* ldsB,
                                             int tid, f32x4 acc[4][4]) {
  int l  = tid & 63;
  int w  = tid >> 6;
  int wr = (w >> 1) * 64;
  int wc = (w & 1) * 64;
  int lr = l & 15;
  int lk = (l >> 4) * 8;
#pragma unroll
  for (int kk = 0; kk < 64; kk += 32) {
    bf16x8 a[4], b[4];
#pragma unroll
    for (int m = 0; m < 4; ++m)
      a[m] = *(const bf16x8*)(ldsA + ((wr + m * 16 + lr) * 64 + kk + lk) * 2);
#pragma unroll
    for (int n = 0; n < 4; ++n)
      b[n] = *(const bf16x8*)(ldsB + ((wc + n * 16 + lr) * 64 + kk + lk) * 2);
#pragma unroll
    for (int m = 0; m < 4; ++m)
#pragma unroll
      for (int n = 0; n < 4; ++n)
        acc[m][n] = __builtin_amdgcn_mfma_f32_16x16x32_bf16(a[m], b[n], acc[m][n], 0, 0, 0);
  }
}

__device__ __forceinline__ void gemm128(const bf16* Atile, const bf16* Wtile,
                                        int K, char* lds, int tid, f32x4 acc[4][4]) {
  const int nk = K / 64;
  stage_tile(Atile, K, 0, lds, tid);
  stage_tile(Wtile, K, 0, lds + 16384, tid);
  __syncthreads();
  int cur = 0;
  for (int t = 0; t < nk; ++t) {
    int nxt = cur ^ 1;
    if (t + 1 < nk) {
      stage_tile(Atile, K, (t + 1) * 64, lds + nxt * 32768, tid);
      stage_tile(Wtile, K, (t + 1) * 64, lds + nxt * 32768 + 16384, tid);
    }
    compute_tile(lds + cur * 32768, lds + cur * 32768 + 16384, tid, acc);
    __syncthreads();
    cur = nxt;
  }
}

// ---------------------------------------------------------------------------
// K1: z = xb @ Wi^T (bf16), gate = silu(xb @ Wg^T) (bf16).  grid(128, 2)
// ---------------------------------------------------------------------------
__global__ __launch_bounds__(256, 2) void k1_zg(const bf16* __restrict__ x,
                                                const bf16* __restrict__ Wi,
                                                const bf16* __restrict__ Wg,
                                                bf16* __restrict__ z,
                                                bf16* __restrict__ gate) {
  __shared__ char lds[65536];
  int tid = threadIdx.x;
  int mb  = blockIdx.x;
  int sel = blockIdx.y;
  const bf16* W = sel ? Wg : Wi;
  f32x4 acc[4][4];
#pragma unroll
  for (int m = 0; m < 4; ++m)
#pragma unroll
    for (int n = 0; n < 4; ++n)
#pragma unroll
      for (int j = 0; j < 4; ++j) acc[m][n][j] = 0.f;

  gemm128(x + (size_t)mb * 128 * DIM, W, DIM, lds, tid, acc);

  int l  = tid & 63, w = tid >> 6;
  int wr = (w >> 1) * 64, wc = (w & 1) * 64;
  int lr = l & 15, lj = (l >> 4) * 4;
  bf16* o = sel ? gate : z;
#pragma unroll
  for (int m = 0; m < 4; ++m)
#pragma unroll
    for (int n = 0; n < 4; ++n)
#pragma unroll
      for (int j = 0; j < 4; ++j) {
        int row = mb * 128 + wr + m * 16 + lj + j;
        int col = wc + n * 16 + lr;
        float v = acc[m][n][j];
        if (sel) v = v / (1.f + expf(-v));   // silu
        o[(size_t)row * SCAN + col] = f2bf(v);
      }
}

// ---------------------------------------------------------------------------
// K2: dt = softplus(z @ Wdt^T + b_dt), Bv = z @ Wb^T, Cv = z @ Wc^T (fp32 out)
// ---------------------------------------------------------------------------
__global__ __launch_bounds__(256, 2) void k2_small(
    const bf16* __restrict__ z, const bf16* __restrict__ Wdt,
    const bf16* __restrict__ Wb, const bf16* __restrict__ Wc,
    const float* __restrict__ bdtf,
    float* __restrict__ dt, float* __restrict__ Bv, float* __restrict__ Cv) {
  __shared__ bf16 wl[160][136];
  __shared__ bf16 zl[64][136];
  int tid = threadIdx.x;
  int m0  = blockIdx.x * 64;

  for (int idx = tid; idx < 160 * 16; idx += 256) {
    int r = idx >> 4, c8 = (idx & 15) << 3;
    const bf16* src;
    if (r < 128)      src = Wdt + r * 128;
    else if (r < 144) src = Wb + (r - 128) * 128;
    else              src = Wc + (r - 144) * 128;
    *(short8*)&wl[r][c8] = *(const short8*)(src + c8);
  }
  for (int idx = tid; idx < 64 * 16; idx += 256) {
    int r = idx >> 4, c8 = (idx & 15) << 3;
    *(short8*)&zl[r][c8] = *(const short8*)(z + (size_t)(m0 + r) * SCAN + c8);
  }
  __syncthreads();

  int l = tid & 63, w = tid >> 6;
  int lr = l & 15, lk = (l >> 4) * 8, lj = (l >> 4) * 4;
  f32x4 acc[10];
#pragma unroll
  for (int n = 0; n < 10; ++n)
#pragma unroll
    for (int j = 0; j < 4; ++j) acc[n][j] = 0.f;

#pragma unroll
  for (int kk = 0; kk < 128; kk += 32) {
    bf16x8 a = *(const bf16x8*)&zl[w * 16 + lr][kk + lk];
#pragma unroll
    for (int n = 0; n < 10; ++n) {
      bf16x8 bfr = *(const bf16x8*)&wl[n * 16 + lr][kk + lk];
      acc[n] = __builtin_amdgcn_mfma_f32_16x16x32_bf16(a, bfr, acc[n], 0, 0, 0);
    }
  }

#pragma unroll
  for (int n = 0; n < 10; ++n) {
    int o = n * 16 + lr;
#pragma unroll
    for (int j = 0; j < 4; ++j) {
      int row = m0 + w * 16 + lj + j;
      float v = acc[n][j];
      if (o < 128) {
        v += bdtf[o];
        v = fmaxf(v, 0.f) + log1pf(expf(-fabsf(v)));   // stable softplus
        dt[(size_t)row * SCAN + o] = v;
      } else if (o < 144) {
        Bv[(size_t)row * STATE + (o - 128)] = v;
      } else {
        Cv[(size_t)row * STATE + (o - 144)] = v;
      }
    }
  }
}

// ---------------------------------------------------------------------------
// K3a: per-chunk local scan. Block = (chunk, b); thread = n; k in registers.
// fin/apr layout: [b][ch][k][n] (coalesced across n).
// ---------------------------------------------------------------------------
__global__ __launch_bounds__(128) void k3a(
    const float* __restrict__ dt, const bf16* __restrict__ z,
    const float* __restrict__ Bv, const float* __restrict__ Aneg,
    float* __restrict__ fin, float* __restrict__ apr) {
  __shared__ float Bl[LCH][STATE];
  int n  = threadIdx.x;
  int ch = blockIdx.x, b = blockIdx.y;
  int t0 = ch * LCH;
  // stage B chunk: LCH*STATE = 512 floats, contiguous; thread loads one float4
  ((float4*)&Bl[0][0])[n] = ((const float4*)(Bv + ((size_t)b * SEQ + t0) * STATE))[n];

  float A[STATE], st[STATE], ap[STATE];
#pragma unroll
  for (int k = 0; k < STATE; ++k) {
    A[k] = Aneg[n * STATE + k];
    st[k] = 0.f; ap[k] = 1.f;
  }
  __syncthreads();

  const float* dtp = dt + ((size_t)b * SEQ + t0) * SCAN + n;
  const bf16*  zp  = z  + ((size_t)b * SEQ + t0) * SCAN + n;
#pragma unroll 4
  for (int t = 0; t < LCH; ++t) {
    float d = dtp[t * SCAN];
    float u = d * bf2f(zp[t * SCAN]);
#pragma unroll
    for (int kg = 0; kg < 4; ++kg) {
      float4 B4 = *(const float4*)&Bl[t][kg * 4];
      float a;
      a = fmaf(d, A[kg*4+0], 1.f); st[kg*4+0] = fmaf(a, st[kg*4+0], u * B4.x); ap[kg*4+0] *= a;
      a = fmaf(d, A[kg*4+1], 1.f); st[kg*4+1] = fmaf(a, st[kg*4+1], u * B4.y); ap[kg*4+1] *= a;
      a = fmaf(d, A[kg*4+2], 1.f); st[kg*4+2] = fmaf(a, st[kg*4+2], u * B4.z); ap[kg*4+2] *= a;
      a = fmaf(d, A[kg*4+3], 1.f); st[kg*4+3] = fmaf(a, st[kg*4+3], u * B4.w); ap[kg*4+3] *= a;
    }
  }
  size_t base = ((size_t)b * NCH + ch) * (STATE * SCAN) + n;
#pragma unroll
  for (int k = 0; k < STATE; ++k) {
    fin[base + k * SCAN] = st[k];
    apr[base + k * SCAN] = ap[k];
  }
}

// ---------------------------------------------------------------------------
// K3b: combine across chunks; apr is overwritten in place with the INCOMING
// state per chunk (read apr/fin, then store inc into apr slot).
// ---------------------------------------------------------------------------
__global__ __launch_bounds__(256) void k3b(const float* __restrict__ fin,
                                           float* __restrict__ apr) {
  int c  = blockIdx.x * 256 + threadIdx.x;   // 0..8191
  int b  = c >> 11;
  int kn = c & 2047;
  float s = 0.f;
#pragma unroll 2
  for (int ch = 0; ch < NCH; ++ch) {
    size_t o = ((size_t)b * NCH + ch) * 2048 + kn;
    float f_ = fin[o], a_ = apr[o];
    apr[o] = s;                  // incoming state for chunk ch
    s = fmaf(a_, s, f_);
  }
}

// ---------------------------------------------------------------------------
// K3c: re-scan with incoming state; yg = (sum_k st*C) * gate (bf16).
// yg may alias z (each element read before written by the same thread).
// ---------------------------------------------------------------------------
__global__ __launch_bounds__(128) void k3c(
    const float* __restrict__ dt, const bf16* z,
    const float* __restrict__ Bv, const float* __restrict__ Cv,
    const float* __restrict__ Aneg, const float* __restrict__ inc,
    const bf16* __restrict__ gate, bf16* yg) {
  __shared__ float Bl[LCH][STATE];
  __shared__ float Cl[LCH][STATE];
  int n  = threadIdx.x;
  int ch = blockIdx.x, b = blockIdx.y;
  int t0 = ch * LCH;
  ((float4*)&Bl[0][0])[n] = ((const float4*)(Bv + ((size_t)b * SEQ + t0) * STATE))[n];
  ((float4*)&Cl[0][0])[n] = ((const float4*)(Cv + ((size_t)b * SEQ + t0) * STATE))[n];

  size_t base = ((size_t)b * NCH + ch) * (STATE * SCAN) + n;
  float A[STATE], st[STATE];
#pragma unroll
  for (int k = 0; k < STATE; ++k) {
    A[k]  = Aneg[n * STATE + k];
    st[k] = inc[base + k * SCAN];
  }
  __syncthreads();

  const float* dtp = dt   + ((size_t)b * SEQ + t0) * SCAN + n;
  const bf16*  zp  = z    + ((size_t)b * SEQ + t0) * SCAN + n;
  const bf16*  gp  = gate + ((size_t)b * SEQ + t0) * SCAN + n;
  bf16*        yp  = yg   + ((size_t)b * SEQ + t0) * SCAN + n;
#pragma unroll 4
  for (int t = 0; t < LCH; ++t) {
    float d = dtp[t * SCAN];
    float u = d * bf2f(zp[t * SCAN]);
    float g = bf2f(gp[t * SCAN]);
    float y0 = 0.f, y1 = 0.f, y2 = 0.f, y3 = 0.f;
#pragma unroll
    for (int kg = 0; kg < 4; ++kg) {
      float4 B4 = *(const float4*)&Bl[t][kg * 4];
      float4 C4 = *(const float4*)&Cl[t][kg * 4];
      float a, p = 0.f;
      a = fmaf(d, A[kg*4+0], 1.f); st[kg*4+0] = fmaf(a, st[kg*4+0], u * B4.x); p = fmaf(st[kg*4+0], C4.x, p);
      a = fmaf(d, A[kg*4+1], 1.f); st[kg*4+1] = fmaf(a, st[kg*4+1], u * B4.y); p = fmaf(st[kg*4+1], C4.y, p);
      a = fmaf(d, A[kg*4+2], 1.f); st[kg*4+2] = fmaf(a, st[kg*4+2], u * B4.z); p = fmaf(st[kg*4+2], C4.z, p);
      a = fmaf(d, A[kg*4+3], 1.f); st[kg*4+3] = fmaf(a, st[kg*4+3], u * B4.w); p = fmaf(st[kg*4+3], C4.w, p);
      if (kg == 0) y0 = p; else if (kg == 1) y1 = p; else if (kg == 2) y2 = p; else y3 = p;
    }
    float y = (y0 + y1) + (y2 + y3);
    yp[t * SCAN] = f2bf(y * g);
  }
}

// ---------------------------------------------------------------------------
// K4: out = yg @ Wo^T -> [16384,2048], stored f32 or bf16 per flag. grid(128,16)
// ---------------------------------------------------------------------------
__global__ __launch_bounds__(256, 2) void k4_out(const bf16* __restrict__ yg,
                                                 const bf16* __restrict__ Wo,
                                                 void* __restrict__ outv,
                                                 const int* __restrict__ flag) {
  __shared__ char lds[65536];
  int tid = threadIdx.x;
  int mb = blockIdx.x, nb = blockIdx.y;
  f32x4 acc[4][4];
#pragma unroll
  for (int m = 0; m < 4; ++m)
#pragma unroll
    for (int n = 0; n < 4; ++n)
#pragma unroll
      for (int j = 0; j < 4; ++j) acc[m][n][j] = 0.f;

  gemm128(yg + (size_t)mb * 128 * SCAN, Wo + (size_t)nb * 128 * SCAN, SCAN, lds, tid, acc);

  int f = *flag;
  int l  = tid & 63, w = tid >> 6;
  int wr = (w >> 1) * 64, wc = (w & 1) * 64;
  int lr = l & 15, lj = (l >> 4) * 4;
#pragma unroll
  for (int m = 0; m < 4; ++m)
#pragma unroll
    for (int n = 0; n < 4; ++n)
#pragma unroll
      for (int j = 0; j < 4; ++j) {
        int row = mb * 128 + wr + m * 16 + lj + j;
        int col = nb * 128 + wc + n * 16 + lr;
        size_t off = (size_t)row * DIM + col;
        float v = acc[m][n][j];
        if (f) ((bf16*)outv)[off] = f2bf(v);
        else   ((float*)outv)[off] = v;
      }
}

// ---------------------------------------------------------------------------
extern "C" void kernel_launch(void* const* d_in, const int* in_sizes, int n_in,
                              void* d_out, int out_size, void* d_ws, size_t ws_size,
                              hipStream_t stream) {
  const void* x     = d_in[0];
  const void* Wi    = d_in[1];
  const void* Wo    = d_in[2];
  const void* A_log = d_in[3];
  const void* Wb    = d_in[4];
  const void* Wc    = d_in[5];
  const void* Wdt   = d_in[6];
  const void* b_dt  = d_in[7];
  const void* Wg    = d_in[8];

  const size_t M = (size_t)BATCH * SEQ;   // 16384
  char* p = (char*)d_ws;
  int*   flag = (int*)p;    p += 256;
  bf16*  xb   = (bf16*)p;   p += M * DIM * 2;
  bf16*  Wib  = (bf16*)p;   p += (size_t)SCAN * DIM * 2;
  bf16*  Wgb  = (bf16*)p;   p += (size_t)SCAN * DIM * 2;
  bf16*  Wob  = (bf16*)p;   p += (size_t)DIM * SCAN * 2;
  bf16*  Wdtb = (bf16*)p;   p += (size_t)SCAN * SCAN * 2;
  bf16*  Wbb  = (bf16*)p;   p += (size_t)STATE * SCAN * 2;
  bf16*  Wcb  = (bf16*)p;   p += (size_t)STATE * SCAN * 2;
  float* bdtf = (float*)p;  p += SCAN * 4;
  float* Anegf= (float*)p;  p += (size_t)SCAN * STATE * 4;
  bf16*  z    = (bf16*)p;   p += M * SCAN * 2;
  bf16*  gate = (bf16*)p;   p += M * SCAN * 2;
  bf16*  yg   = z;                                   // alias: k3c reads z[t,n] before writing yg[t,n]
  float* dt   = (float*)p;  p += M * SCAN * 4;
  float* Bv   = (float*)p;  p += M * STATE * 4;
  float* Cv   = (float*)p;  p += M * STATE * 4;
  float* fin  = (float*)p;  p += (size_t)BATCH * NCH * SCAN * STATE * 4;
  float* apr  = (float*)p;  p += (size_t)BATCH * NCH * SCAN * STATE * 4;   // becomes inc after k3b

  kprobe  <<<1, 64, 0, stream>>>((const unsigned short*)x, flag);
  kconv_x <<<2048, 256, 0, stream>>>(x, xb, flag);
  kconv_w <<<256, 256, 0, stream>>>(Wi, Wg, Wo, Wdt, Wb, Wc, b_dt, A_log,
                                    Wib, Wgb, Wob, Wdtb, Wbb, Wcb, bdtf, Anegf, flag);
  k1_zg   <<<dim3(128, 2), 256, 0, stream>>>(xb, Wib, Wgb, z, gate);
  k2_small<<<dim3(256), 256, 0, stream>>>(z, Wdtb, Wbb, Wcb, bdtf, dt, Bv, Cv);
  k3a     <<<dim3(NCH, BATCH), 128, 0, stream>>>(dt, z, Bv, Anegf, fin, apr);
  k3b     <<<dim3(32), 256, 0, stream>>>(fin, apr);
  k3c     <<<dim3(NCH, BATCH), 128, 0, stream>>>(dt, z, Bv, Cv, Anegf, apr, gate, yg);
  k4_out  <<<dim3(128, 16), 256, 0, stream>>>(yg, Wob, d_out, flag);
}

// Round 4
// 178.101 us; speedup vs baseline: 1.4243x; 1.1972x over previous
//
#include <hip/hip_runtime.h>
#include <hip/hip_bf16.h>
#include <math.h>

using bf16 = __hip_bfloat16;
typedef __attribute__((ext_vector_type(8))) short bf16x8;
typedef __attribute__((ext_vector_type(8))) short short8;
typedef __attribute__((ext_vector_type(4))) float f32x4;

#define AS1 __attribute__((address_space(1)))
#define AS3 __attribute__((address_space(3)))

constexpr int BATCH = 4;
constexpr int SEQ   = 4096;
constexpr int DIM   = 2048;
constexpr int SCAN  = 128;
constexpr int STATE = 16;
constexpr int LCH   = 32;         // scan chunk length
constexpr int NCH   = SEQ / LCH;  // 128 chunks

__device__ __forceinline__ float bf2f(bf16 v) { return __bfloat162float(v); }
__device__ __forceinline__ bf16  f2bf(float v) { return __float2bfloat16(v); }

// ---------------------------------------------------------------------------
// Probe: decide whether device buffers are f32 (flag=0) or bf16 (flag=1).
// ---------------------------------------------------------------------------
__global__ void kprobe(const unsigned short* __restrict__ x, int* __restrict__ flag) {
  int t = threadIdx.x;   // 64 threads
  int cnt = 0;
#pragma unroll
  for (int i = 0; i < 8; ++i) {
    unsigned short u = x[t * 8 + i];
    int e = (u >> 7) & 0xFF;
    if (e >= 107 && e <= 147) ++cnt;
  }
  cnt += __shfl_xor(cnt, 1);  cnt += __shfl_xor(cnt, 2);
  cnt += __shfl_xor(cnt, 4);  cnt += __shfl_xor(cnt, 8);
  cnt += __shfl_xor(cnt, 16); cnt += __shfl_xor(cnt, 32);
  if (t == 0) *flag = (cnt >= 410) ? 1 : 0;
}

// ---------------------------------------------------------------------------
// Weights -> bf16 ws copies; b_dt -> f32; A_log -> Aneg = -exp(A_log) (f32)
// ---------------------------------------------------------------------------
__device__ __forceinline__ void conv_b(const void* src, bf16* dst, int n, int f,
                                       int gtid, int nt) {
  if (f) { const bf16* s = (const bf16*)src;  for (int i = gtid; i < n; i += nt) dst[i] = s[i]; }
  else   { const float* s = (const float*)src; for (int i = gtid; i < n; i += nt) dst[i] = f2bf(s[i]); }
}
__device__ __forceinline__ void conv_f(const void* src, float* dst, int n, int f,
                                       int gtid, int nt) {
  if (f) { const bf16* s = (const bf16*)src;  for (int i = gtid; i < n; i += nt) dst[i] = bf2f(s[i]); }
  else   { const float* s = (const float*)src; for (int i = gtid; i < n; i += nt) dst[i] = s[i]; }
}
__device__ __forceinline__ void conv_aneg(const void* src, float* dst, int n, int f,
                                          int gtid, int nt) {
  if (f) { const bf16* s = (const bf16*)src;  for (int i = gtid; i < n; i += nt) dst[i] = -expf(bf2f(s[i])); }
  else   { const float* s = (const float*)src; for (int i = gtid; i < n; i += nt) dst[i] = -expf(s[i]); }
}

__global__ __launch_bounds__(256) void kconv_w(
    const void* Wi, const void* Wg, const void* Wo, const void* Wdt,
    const void* Wb, const void* Wc, const void* bdt, const void* Alog,
    bf16* Wib, bf16* Wgb, bf16* Wob, bf16* Wdtb, bf16* Wbb, bf16* Wcb,
    float* bdtf, float* Anegf, const int* __restrict__ flag) {
  int f = *flag;
  int nt = gridDim.x * blockDim.x;
  int g  = blockIdx.x * blockDim.x + threadIdx.x;
  conv_b(Wi,  Wib,  SCAN * DIM,  f, g, nt);
  conv_b(Wg,  Wgb,  SCAN * DIM,  f, g, nt);
  conv_b(Wo,  Wob,  DIM * SCAN,  f, g, nt);
  conv_b(Wdt, Wdtb, SCAN * SCAN, f, g, nt);
  conv_b(Wb,  Wbb,  STATE * SCAN, f, g, nt);
  conv_b(Wc,  Wcb,  STATE * SCAN, f, g, nt);
  conv_f(bdt,  bdtf,  SCAN,          f, g, nt);
  conv_aneg(Alog, Anegf, SCAN * STATE, f, g, nt);
}

// ---------------------------------------------------------------------------
// K1 (fused): z = x @ Wi^T, gate = silu(x @ Wg^T); converts x f32->bf16 on the
// fly (reg-staged A). BM=64, BN=256 (z|gate), BK=64, 256 thr, grid 256.
// LDS per buffer: A [64][64] bf16 @0 (8K), B [256][64] bf16 @8K (32K) = 40K; x2.
// ---------------------------------------------------------------------------
struct ARegs { float4 v[4]; };

__device__ __forceinline__ ARegs loadA(const void* xin, size_t rowbase, int k0,
                                       int ac, int f) {
  ARegs r;
  if (f) {  // bf16 input: 16 elems = 32 B
    const float4* s = (const float4*)((const bf16*)xin + rowbase + k0 + ac);
    r.v[0] = s[0]; r.v[1] = s[1];
  } else {  // f32 input: 16 elems = 64 B
    const float4* s = (const float4*)((const float*)xin + rowbase + k0 + ac);
    r.v[0] = s[0]; r.v[1] = s[1]; r.v[2] = s[2]; r.v[3] = s[3];
  }
  return r;
}

__device__ __forceinline__ void writeA(char* abuf, int ar, int ac, const ARegs& rg, int f) {
  char* dst = abuf + ar * 128 + ac * 2;
  if (f) {
    *(float4*)dst = rg.v[0];
    *(float4*)(dst + 16) = rg.v[1];
  } else {
    union { short8 s; bf16 b[8]; } u0, u1;
    const float* fv = (const float*)&rg.v[0];
#pragma unroll
    for (int i = 0; i < 8; ++i) u0.b[i] = f2bf(fv[i]);
#pragma unroll
    for (int i = 0; i < 8; ++i) u1.b[i] = f2bf(fv[8 + i]);
    *(short8*)dst = u0.s;
    *(short8*)(dst + 16) = u1.s;
  }
}

__device__ __forceinline__ void stageB(const bf16* __restrict__ Wi,
                                       const bf16* __restrict__ Wg,
                                       int k0, char* bbuf, int tid) {
  int w = tid >> 6;
#pragma unroll
  for (int i = 0; i < 4; ++i) {
    int off = i * 4096 + tid * 16;
    int r = off >> 7;            // row (128 B per row)
    int c = (off & 127) >> 1;    // elem col
    __builtin_amdgcn_global_load_lds((const AS1 void*)(Wi + (size_t)r * DIM + k0 + c),
                                     (AS3 void*)(bbuf + i * 4096 + w * 1024), 16, 0, 0);
    __builtin_amdgcn_global_load_lds((const AS1 void*)(Wg + (size_t)r * DIM + k0 + c),
                                     (AS3 void*)(bbuf + 16384 + i * 4096 + w * 1024), 16, 0, 0);
  }
}

__device__ __forceinline__ void compute64x256(const char* abuf, const char* bbuf,
                                              int tid, f32x4 acc[4][4]) {
  int l = tid & 63, w = tid >> 6;
  int lr = l & 15, lk = (l >> 4) * 8;
#pragma unroll
  for (int kk = 0; kk < 64; kk += 32) {
    bf16x8 a[4], b[4];
#pragma unroll
    for (int m = 0; m < 4; ++m)
      a[m] = *(const bf16x8*)(abuf + ((m * 16 + lr) * 64 + kk + lk) * 2);
#pragma unroll
    for (int n = 0; n < 4; ++n)
      b[n] = *(const bf16x8*)(bbuf + ((w * 64 + n * 16 + lr) * 64 + kk + lk) * 2);
#pragma unroll
    for (int m = 0; m < 4; ++m)
#pragma unroll
      for (int n = 0; n < 4; ++n)
        acc[m][n] = __builtin_amdgcn_mfma_f32_16x16x32_bf16(a[m], b[n], acc[m][n], 0, 0, 0);
  }
}

__global__ __launch_bounds__(256) void k1_zg(const void* __restrict__ xin,
                                             const bf16* __restrict__ Wi,
                                             const bf16* __restrict__ Wg,
                                             bf16* __restrict__ z,
                                             bf16* __restrict__ gate,
                                             const int* __restrict__ flag) {
  __shared__ char lds[81920];
  int tid = threadIdx.x;
  int mb  = blockIdx.x;
  int f   = *flag;
  int ar  = tid >> 2;             // A-stage row 0..63
  int ac  = (tid & 3) * 16;       // A-stage col (elems)
  size_t xrow = ((size_t)mb * 64 + ar) * DIM;

  f32x4 acc[4][4];
#pragma unroll
  for (int m = 0; m < 4; ++m)
#pragma unroll
    for (int n = 0; n < 4; ++n)
#pragma unroll
      for (int j = 0; j < 4; ++j) acc[m][n][j] = 0.f;

  const int NK = DIM / 64;   // 32
  stageB(Wi, Wg, 0, lds + 8192, tid);
  { ARegs r0 = loadA(xin, xrow, 0, ac, f); writeA(lds, ar, ac, r0, f); }
  __syncthreads();

  int cur = 0;
  for (int t = 0; t < NK; ++t) {
    char* curb = lds + cur * 40960;
    char* nxtb = lds + (cur ^ 1) * 40960;
    ARegs rg;
    if (t + 1 < NK) {
      stageB(Wi, Wg, (t + 1) * 64, nxtb + 8192, tid);   // async, drains at barrier
      rg = loadA(xin, xrow, (t + 1) * 64, ac, f);       // in flight under MFMA
    }
    compute64x256(curb, curb + 8192, tid, acc);
    if (t + 1 < NK) writeA(nxtb, ar, ac, rg, f);
    __syncthreads();
    cur ^= 1;
  }

  int l = tid & 63, w = tid >> 6;
  int sel = w >> 1;               // 0 -> z, 1 -> gate
  int cb  = (w & 1) * 64;
  int lr = l & 15, lj = (l >> 4) * 4;
  bf16* o = sel ? gate : z;
#pragma unroll
  for (int m = 0; m < 4; ++m)
#pragma unroll
    for (int n = 0; n < 4; ++n)
#pragma unroll
      for (int j = 0; j < 4; ++j) {
        int row = mb * 64 + m * 16 + lj + j;
        int col = cb + n * 16 + lr;
        float v = acc[m][n][j];
        if (sel) v = v / (1.f + expf(-v));   // silu
        o[(size_t)row * SCAN + col] = f2bf(v);
      }
}

// ---------------------------------------------------------------------------
// K2: dt = softplus(z @ Wdt^T + b_dt), Bv = z @ Wb^T, Cv = z @ Wc^T (fp32 out)
// ---------------------------------------------------------------------------
__global__ __launch_bounds__(256, 2) void k2_small(
    const bf16* __restrict__ z, const bf16* __restrict__ Wdt,
    const bf16* __restrict__ Wb, const bf16* __restrict__ Wc,
    const float* __restrict__ bdtf,
    float* __restrict__ dt, float* __restrict__ Bv, float* __restrict__ Cv) {
  __shared__ bf16 wl[160][136];
  __shared__ bf16 zl[64][136];
  int tid = threadIdx.x;
  int m0  = blockIdx.x * 64;

  for (int idx = tid; idx < 160 * 16; idx += 256) {
    int r = idx >> 4, c8 = (idx & 15) << 3;
    const bf16* src;
    if (r < 128)      src = Wdt + r * 128;
    else if (r < 144) src = Wb + (r - 128) * 128;
    else              src = Wc + (r - 144) * 128;
    *(short8*)&wl[r][c8] = *(const short8*)(src + c8);
  }
  for (int idx = tid; idx < 64 * 16; idx += 256) {
    int r = idx >> 4, c8 = (idx & 15) << 3;
    *(short8*)&zl[r][c8] = *(const short8*)(z + (size_t)(m0 + r) * SCAN + c8);
  }
  __syncthreads();

  int l = tid & 63, w = tid >> 6;
  int lr = l & 15, lk = (l >> 4) * 8, lj = (l >> 4) * 4;
  f32x4 acc[10];
#pragma unroll
  for (int n = 0; n < 10; ++n)
#pragma unroll
    for (int j = 0; j < 4; ++j) acc[n][j] = 0.f;

#pragma unroll
  for (int kk = 0; kk < 128; kk += 32) {
    bf16x8 a = *(const bf16x8*)&zl[w * 16 + lr][kk + lk];
#pragma unroll
    for (int n = 0; n < 10; ++n) {
      bf16x8 bfr = *(const bf16x8*)&wl[n * 16 + lr][kk + lk];
      acc[n] = __builtin_amdgcn_mfma_f32_16x16x32_bf16(a, bfr, acc[n], 0, 0, 0);
    }
  }

#pragma unroll
  for (int n = 0; n < 10; ++n) {
    int o = n * 16 + lr;
#pragma unroll
    for (int j = 0; j < 4; ++j) {
      int row = m0 + w * 16 + lj + j;
      float v = acc[n][j];
      if (o < 128) {
        v += bdtf[o];
        v = fmaxf(v, 0.f) + log1pf(expf(-fabsf(v)));   // stable softplus
        dt[(size_t)row * SCAN + o] = v;
      } else if (o < 144) {
        Bv[(size_t)row * STATE + (o - 128)] = v;
      } else {
        Cv[(size_t)row * STATE + (o - 144)] = v;
      }
    }
  }
}

// ---------------------------------------------------------------------------
// K3a: per-chunk local scan. Block = (chunk, b); thread = n; k in registers.
// fin/apr layout: [b][ch][k][n] (coalesced across n).
// ---------------------------------------------------------------------------
__global__ __launch_bounds__(128) void k3a(
    const float* __restrict__ dt, const bf16* __restrict__ z,
    const float* __restrict__ Bv, const float* __restrict__ Aneg,
    float* __restrict__ fin, float* __restrict__ apr) {
  __shared__ float Bl[LCH][STATE];
  int n  = threadIdx.x;
  int ch = blockIdx.x, b = blockIdx.y;
  int t0 = ch * LCH;
  ((float4*)&Bl[0][0])[n] = ((const float4*)(Bv + ((size_t)b * SEQ + t0) * STATE))[n];

  float A[STATE], st[STATE], ap[STATE];
#pragma unroll
  for (int k = 0; k < STATE; ++k) {
    A[k] = Aneg[n * STATE + k];
    st[k] = 0.f; ap[k] = 1.f;
  }
  __syncthreads();

  const float* dtp = dt + ((size_t)b * SEQ + t0) * SCAN + n;
  const bf16*  zp  = z  + ((size_t)b * SEQ + t0) * SCAN + n;
#pragma unroll 4
  for (int t = 0; t < LCH; ++t) {
    float d = dtp[t * SCAN];
    float u = d * bf2f(zp[t * SCAN]);
#pragma unroll
    for (int kg = 0; kg < 4; ++kg) {
      float4 B4 = *(const float4*)&Bl[t][kg * 4];
      float a;
      a = fmaf(d, A[kg*4+0], 1.f); st[kg*4+0] = fmaf(a, st[kg*4+0], u * B4.x); ap[kg*4+0] *= a;
      a = fmaf(d, A[kg*4+1], 1.f); st[kg*4+1] = fmaf(a, st[kg*4+1], u * B4.y); ap[kg*4+1] *= a;
      a = fmaf(d, A[kg*4+2], 1.f); st[kg*4+2] = fmaf(a, st[kg*4+2], u * B4.z); ap[kg*4+2] *= a;
      a = fmaf(d, A[kg*4+3], 1.f); st[kg*4+3] = fmaf(a, st[kg*4+3], u * B4.w); ap[kg*4+3] *= a;
    }
  }
  size_t base = ((size_t)b * NCH + ch) * (STATE * SCAN) + n;
#pragma unroll
  for (int k = 0; k < STATE; ++k) {
    fin[base + k * SCAN] = st[k];
    apr[base + k * SCAN] = ap[k];
  }
}

// ---------------------------------------------------------------------------
// K3b: combine across chunks; apr is overwritten in place with the INCOMING
// state per chunk. grid(128) x 64 thr -> 128 CUs active.
// ---------------------------------------------------------------------------
__global__ __launch_bounds__(64) void k3b(const float* __restrict__ fin,
                                          float* __restrict__ apr) {
  int c  = blockIdx.x * 64 + threadIdx.x;   // 0..8191
  int b  = c >> 11;
  int kn = c & 2047;
  float s = 0.f;
#pragma unroll 4
  for (int ch = 0; ch < NCH; ++ch) {
    size_t o = ((size_t)b * NCH + ch) * 2048 + kn;
    float f_ = fin[o], a_ = apr[o];
    apr[o] = s;                  // incoming state for chunk ch
    s = fmaf(a_, s, f_);
  }
}

// ---------------------------------------------------------------------------
// K3c: re-scan with incoming state; yg = (sum_k st*C) * gate (bf16).
// yg may alias z (each element read before written by the same thread).
// ---------------------------------------------------------------------------
__global__ __launch_bounds__(128) void k3c(
    const float* __restrict__ dt, const bf16* z,
    const float* __restrict__ Bv, const float* __restrict__ Cv,
    const float* __restrict__ Aneg, const float* __restrict__ inc,
    const bf16* __restrict__ gate, bf16* yg) {
  __shared__ float Bl[LCH][STATE];
  __shared__ float Cl[LCH][STATE];
  int n  = threadIdx.x;
  int ch = blockIdx.x, b = blockIdx.y;
  int t0 = ch * LCH;
  ((float4*)&Bl[0][0])[n] = ((const float4*)(Bv + ((size_t)b * SEQ + t0) * STATE))[n];
  ((float4*)&Cl[0][0])[n] = ((const float4*)(Cv + ((size_t)b * SEQ + t0) * STATE))[n];

  size_t base = ((size_t)b * NCH + ch) * (STATE * SCAN) + n;
  float A[STATE], st[STATE];
#pragma unroll
  for (int k = 0; k < STATE; ++k) {
    A[k]  = Aneg[n * STATE + k];
    st[k] = inc[base + k * SCAN];
  }
  __syncthreads();

  const float* dtp = dt   + ((size_t)b * SEQ + t0) * SCAN + n;
  const bf16*  zp  = z    + ((size_t)b * SEQ + t0) * SCAN + n;
  const bf16*  gp  = gate + ((size_t)b * SEQ + t0) * SCAN + n;
  bf16*        yp  = yg   + ((size_t)b * SEQ + t0) * SCAN + n;
#pragma unroll 4
  for (int t = 0; t < LCH; ++t) {
    float d = dtp[t * SCAN];
    float u = d * bf2f(zp[t * SCAN]);
    float g = bf2f(gp[t * SCAN]);
    float y0 = 0.f, y1 = 0.f, y2 = 0.f, y3 = 0.f;
#pragma unroll
    for (int kg = 0; kg < 4; ++kg) {
      float4 B4 = *(const float4*)&Bl[t][kg * 4];
      float4 C4 = *(const float4*)&Cl[t][kg * 4];
      float a, p = 0.f;
      a = fmaf(d, A[kg*4+0], 1.f); st[kg*4+0] = fmaf(a, st[kg*4+0], u * B4.x); p = fmaf(st[kg*4+0], C4.x, p);
      a = fmaf(d, A[kg*4+1], 1.f); st[kg*4+1] = fmaf(a, st[kg*4+1], u * B4.y); p = fmaf(st[kg*4+1], C4.y, p);
      a = fmaf(d, A[kg*4+2], 1.f); st[kg*4+2] = fmaf(a, st[kg*4+2], u * B4.z); p = fmaf(st[kg*4+2], C4.z, p);
      a = fmaf(d, A[kg*4+3], 1.f); st[kg*4+3] = fmaf(a, st[kg*4+3], u * B4.w); p = fmaf(st[kg*4+3], C4.w, p);
      if (kg == 0) y0 = p; else if (kg == 1) y1 = p; else if (kg == 2) y2 = p; else y3 = p;
    }
    float y = (y0 + y1) + (y2 + y3);
    yp[t * SCAN] = f2bf(y * g);
  }
}

// ---------------------------------------------------------------------------
// GEMM helpers for K4 (bf16 LDS staging via global_load_lds)
// ---------------------------------------------------------------------------
__device__ __forceinline__ void stage_tile(const bf16* __restrict__ src, int ld, int k0,
                                           char* ldsbuf, int tid) {
  int w = tid >> 6;
#pragma unroll
  for (int i = 0; i < 4; ++i) {
    int off = i * 4096 + tid * 16;
    int r   = off >> 7;
    int c   = (off & 127) >> 1;
    const bf16* g = src + (size_t)r * ld + (k0 + c);
    char* lb = ldsbuf + i * 4096 + w * 1024;
    __builtin_amdgcn_global_load_lds((const AS1 void*)g, (AS3 void*)lb, 16, 0, 0);
  }
}

__device__ __forceinline__ void compute_tile(const char* ldsA, const char* ldsB,
                                             int tid, f32x4 acc[4][4]) {
  int l  = tid & 63;
  int w  = tid >> 6;
  int wr = (w >> 1) * 64;
  int wc = (w & 1) * 64;
  int lr = l & 15;
  int lk = (l >> 4) * 8;
#pragma unroll
  for (int kk = 0; kk < 64; kk += 32) {
    bf16x8 a[4], b[4];
#pragma unroll
    for (int m = 0; m < 4; ++m)
      a[m] = *(const bf16x8*)(ldsA + ((wr + m * 16 + lr) * 64 + kk + lk) * 2);
#pragma unroll
    for (int n = 0; n < 4; ++n)
      b[n] = *(const bf16x8*)(ldsB + ((wc + n * 16 + lr) * 64 + kk + lk) * 2);
#pragma unroll
    for (int m = 0; m < 4; ++m)
#pragma unroll
      for (int n = 0; n < 4; ++n)
        acc[m][n] = __builtin_amdgcn_mfma_f32_16x16x32_bf16(a[m], b[n], acc[m][n], 0, 0, 0);
  }
}

// ---------------------------------------------------------------------------
// K4: out = yg @ Wo^T -> [16384,2048], stored f32 or bf16 per flag. grid(128,16)
// ---------------------------------------------------------------------------
__global__ __launch_bounds__(256, 2) void k4_out(const bf16* __restrict__ yg,
                                                 const bf16* __restrict__ Wo,
                                                 void* __restrict__ outv,
                                                 const int* __restrict__ flag) {
  __shared__ char lds[65536];
  int tid = threadIdx.x;
  int mb = blockIdx.x, nb = blockIdx.y;
  f32x4 acc[4][4];
#pragma unroll
  for (int m = 0; m < 4; ++m)
#pragma unroll
    for (int n = 0; n < 4; ++n)
#pragma unroll
      for (int j = 0; j < 4; ++j) acc[m][n][j] = 0.f;

  const bf16* At = yg + (size_t)mb * 128 * SCAN;
  const bf16* Wt = Wo + (size_t)nb * 128 * SCAN;
  stage_tile(At, SCAN, 0, lds, tid);
  stage_tile(Wt, SCAN, 0, lds + 16384, tid);
  __syncthreads();
  stage_tile(At, SCAN, 64, lds + 32768, tid);
  stage_tile(Wt, SCAN, 64, lds + 32768 + 16384, tid);
  compute_tile(lds, lds + 16384, tid, acc);
  __syncthreads();
  compute_tile(lds + 32768, lds + 32768 + 16384, tid, acc);

  int f = *flag;
  int l  = tid & 63, w = tid >> 6;
  int wr = (w >> 1) * 64, wc = (w & 1) * 64;
  int lr = l & 15, lj = (l >> 4) * 4;
#pragma unroll
  for (int m = 0; m < 4; ++m)
#pragma unroll
    for (int n = 0; n < 4; ++n)
#pragma unroll
      for (int j = 0; j < 4; ++j) {
        int row = mb * 128 + wr + m * 16 + lj + j;
        int col = nb * 128 + wc + n * 16 + lr;
        size_t off = (size_t)row * DIM + col;
        float v = acc[m][n][j];
        if (f) ((bf16*)outv)[off] = f2bf(v);
        else   ((float*)outv)[off] = v;
      }
}

// ---------------------------------------------------------------------------
extern "C" void kernel_launch(void* const* d_in, const int* in_sizes, int n_in,
                              void* d_out, int out_size, void* d_ws, size_t ws_size,
                              hipStream_t stream) {
  const void* x     = d_in[0];
  const void* Wi    = d_in[1];
  const void* Wo    = d_in[2];
  const void* A_log = d_in[3];
  const void* Wb    = d_in[4];
  const void* Wc    = d_in[5];
  const void* Wdt   = d_in[6];
  const void* b_dt  = d_in[7];
  const void* Wg    = d_in[8];

  const size_t M = (size_t)BATCH * SEQ;   // 16384
  char* p = (char*)d_ws;
  int*   flag = (int*)p;    p += 256;
  bf16*  Wib  = (bf16*)p;   p += (size_t)SCAN * DIM * 2;
  bf16*  Wgb  = (bf16*)p;   p += (size_t)SCAN * DIM * 2;
  bf16*  Wob  = (bf16*)p;   p += (size_t)DIM * SCAN * 2;
  bf16*  Wdtb = (bf16*)p;   p += (size_t)SCAN * SCAN * 2;
  bf16*  Wbb  = (bf16*)p;   p += (size_t)STATE * SCAN * 2;
  bf16*  Wcb  = (bf16*)p;   p += (size_t)STATE * SCAN * 2;
  float* bdtf = (float*)p;  p += SCAN * 4;
  float* Anegf= (float*)p;  p += (size_t)SCAN * STATE * 4;
  bf16*  z    = (bf16*)p;   p += M * SCAN * 2;
  bf16*  gate = (bf16*)p;   p += M * SCAN * 2;
  bf16*  yg   = z;                                   // alias: k3c reads z before writing yg
  float* dt   = (float*)p;  p += M * SCAN * 4;
  float* Bv   = (float*)p;  p += M * STATE * 4;
  float* Cv   = (float*)p;  p += M * STATE * 4;
  float* fin  = (float*)p;  p += (size_t)BATCH * NCH * SCAN * STATE * 4;
  float* apr  = (float*)p;  p += (size_t)BATCH * NCH * SCAN * STATE * 4;   // becomes inc after k3b

  kprobe  <<<1, 64, 0, stream>>>((const unsigned short*)x, flag);
  kconv_w <<<256, 256, 0, stream>>>(Wi, Wg, Wo, Wdt, Wb, Wc, b_dt, A_log,
                                    Wib, Wgb, Wob, Wdtb, Wbb, Wcb, bdtf, Anegf, flag);
  k1_zg   <<<dim3(256), 256, 0, stream>>>(x, Wib, Wgb, z, gate, flag);
  k2_small<<<dim3(256), 256, 0, stream>>>(z, Wdtb, Wbb, Wcb, bdtf, dt, Bv, Cv);
  k3a     <<<dim3(NCH, BATCH), 128, 0, stream>>>(dt, z, Bv, Anegf, fin, apr);
  k3b     <<<dim3(128), 64, 0, stream>>>(fin, apr);
  k3c     <<<dim3(NCH, BATCH), 128, 0, stream>>>(dt, z, Bv, Cv, Anegf, apr, gate, yg);
  k4_out  <<<dim3(128, 16), 256, 0, stream>>>(yg, Wob, d_out, flag);
}